// Round 16
// baseline (182.856 us; speedup 1.0000x reference)
//
#include <hip/hip_runtime.h>

#define HEADS 32
#define DK    64
#define NSEQ  2048
#define BATCH 2
#define DIN   512
#define INNER 2048  // HEADS*DK

typedef float f32x2 __attribute__((ext_vector_type(2)));
typedef float f32x4 __attribute__((ext_vector_type(4)));
typedef float f32x16 __attribute__((ext_vector_type(16)));
typedef short s16x8 __attribute__((ext_vector_type(8)));
typedef short s16x4 __attribute__((ext_vector_type(4)));
typedef unsigned u32x2 __attribute__((ext_vector_type(2)));
typedef unsigned u32x4 __attribute__((ext_vector_type(4)));

#define AS1 __attribute__((address_space(1)))
#define AS3 __attribute__((address_space(3)))

__device__ __forceinline__ short f2b(float f) {
  unsigned u = __float_as_uint(f);
  u += 0x7fffu + ((u >> 16) & 1u);   // round-to-nearest-even
  return (short)(u >> 16);
}

__device__ __forceinline__ unsigned cvt_pk_bf16(float lo, float hi) {
  unsigned r;
  asm("v_cvt_pk_bf16_f32 %0, %1, %2" : "=v"(r) : "v"(lo), "v"(hi));
  return r;
}

// cross-half (lane ^ 32) add via permlane32_swap (full-rate VALU, no LDS)
__device__ __forceinline__ float xhalf_add(float v) {
  u32x2 r = __builtin_amdgcn_permlane32_swap(__float_as_uint(v), __float_as_uint(v),
                                             false, false);
  return __uint_as_float(r[0]) + __uint_as_float(r[1]);
}

// async global->LDS, 16B per lane; lds dest = wave-uniform base + lane*16
__device__ __forceinline__ void gll16(const short* gp, short* lp) {
  __builtin_amdgcn_global_load_lds((const AS1 unsigned*)gp, (AS3 unsigned*)lp, 16, 0, 0);
}

// A-frag-linear (16x16x32 A operand), unit = 16 rows x 32 k = 512 shorts:
//   lin = (m>>4)*(K*16) + (k>>5)*512 + (m&15)*8 + ((k>>3)&3)*128 + (k&7)
// B-frag-linear identical with n in place of m.
// Q/K attn layout per (b,h): lin = (n>>5)*2048 + (dk>>4)*512 + ((dk>>3)&1)*256 + (n&31)*8 + (dk&7)
// V  attn layout per (b,h): lin = (n>>5)*2048 + ((n>>4)&1)*1024 + (dk>>5)*512 + ((n>>3)&1)*256 + (dk&31)*8 + (n&7)

// ---------- fused preprocessing: cvt(x) + transpose(Wq,Wk,Wv,Wz), one launch ----------
__global__ __launch_bounds__(256) void k_prep(const float* __restrict__ x,
                                              const float* __restrict__ Wq,
                                              const float* __restrict__ Wk,
                                              const float* __restrict__ Wv,
                                              const float* __restrict__ Wz,
                                              short* __restrict__ xb,
                                              short* __restrict__ wqkv,
                                              short* __restrict__ wzt) {
  const int bid = blockIdx.x;
  if (bid < 1024) {
    int t = bid * 256 + threadIdx.x;
    int m = t >> 6, kc = t & 63;
    const float* src = x + (size_t)m * 512 + kc * 8;
    float4 v0 = *reinterpret_cast<const float4*>(src);
    float4 v1 = *reinterpret_cast<const float4*>(src + 4);
    s16x8 o;
    o[0] = f2b(v0.x); o[1] = f2b(v0.y); o[2] = f2b(v0.z); o[3] = f2b(v0.w);
    o[4] = f2b(v1.x); o[5] = f2b(v1.y); o[6] = f2b(v1.z); o[7] = f2b(v1.w);
    size_t lin = (size_t)(m >> 4) * 8192 + (kc >> 2) * 512 + (kc & 3) * 128 + (m & 15) * 8;
    *reinterpret_cast<s16x8*>(xb + lin) = o;
    return;
  }
  __shared__ float tile[64][65];
  const float* in; short* out; int R, C, bx, by;
  if (bid < 1792) {
    int z = (bid - 1024) >> 8, inner = (bid - 1024) & 255;
    in = z == 0 ? Wq : z == 1 ? Wk : Wv;
    out = wqkv + (size_t)z * 1048576;
    R = DIN; C = INNER;
    bx = inner & 31; by = inner >> 5;
  } else {
    int inner = bid - 1792;
    in = Wz; out = wzt; R = INNER; C = DIN;
    bx = inner & 7; by = inner >> 3;
  }
  const int tc = bx * 64, tr = by * 64;
  const int tx = threadIdx.x & 63;
  const int ty = threadIdx.x >> 6;
#pragma unroll
  for (int rr = ty; rr < 64; rr += 4)
    tile[rr][tx] = in[(size_t)(tr + rr) * C + tc + tx];
  __syncthreads();
#pragma unroll
  for (int rr = ty; rr < 64; rr += 4) {
    int n = tc + rr, k = tr + tx;
    size_t lin = (size_t)(n >> 4) * ((size_t)R * 16) + (k >> 5) * 512 +
                 ((k >> 3) & 3) * 128 + (n & 15) * 8 + (k & 7);
    out[lin] = f2b(tile[tx][rr]);
  }
}

// -------- fused QKV projection GEMM: M=4096, N=6144, K=512 --------
__global__ __launch_bounds__(256) void k_gemm_qkv(const short* __restrict__ A,
                                                  const short* __restrict__ Bw,
                                                  short* __restrict__ Qb,
                                                  short* __restrict__ Kb,
                                                  short* __restrict__ Vb) {
  __shared__ short sA[2][4096];
  __shared__ short sB[2][4096];
  const int bm = blockIdx.x * 128;
  const int bn = blockIdx.y * 128;
  const int wave = threadIdx.x >> 6, lane = threadIdx.x & 63;
  const int l16 = lane & 15, g = lane >> 4;
  const int wr = wave >> 1, wc = wave & 1;

  const short* Au = A + ((size_t)(bm >> 4) + wave) * 8192 + lane * 8;
  const short* Bu = Bw + ((size_t)(bn >> 4) + wave) * 8192 + lane * 8;

  f32x4 acc[4][4] = {};

  auto stage = [&](int buf, int kt) {
    gll16(Au + kt * 512,              &sA[buf][wave * 512]);
    gll16(Au + 4 * 8192 + kt * 512,   &sA[buf][(wave + 4) * 512]);
    gll16(Bu + kt * 512,              &sB[buf][wave * 512]);
    gll16(Bu + 4 * 8192 + kt * 512,   &sB[buf][(wave + 4) * 512]);
  };

  stage(0, 0);
  __syncthreads();
  int cur = 0;
  for (int kt = 0; kt < 16; ++kt) {
    if (kt + 1 < 16) stage(cur ^ 1, kt + 1);
    s16x8 a[4], b[4];
#pragma unroll
    for (int i = 0; i < 4; i++)
      a[i] = *reinterpret_cast<const s16x8*>(&sA[cur][(wr * 4 + i) * 512 + lane * 8]);
#pragma unroll
    for (int c = 0; c < 4; c++)
      b[c] = *reinterpret_cast<const s16x8*>(&sB[cur][(wc * 4 + c) * 512 + lane * 8]);
#pragma unroll
    for (int i = 0; i < 4; i++)
#pragma unroll
      for (int c = 0; c < 4; c++)
        acc[i][c] = __builtin_amdgcn_mfma_f32_16x16x32_bf16(a[i], b[c], acc[i][c], 0, 0, 0);
    if (kt + 1 < 16) { __syncthreads(); cur ^= 1; }
  }

  const int proj = bn >> 11;
#pragma unroll
  for (int i = 0; i < 4; i++)
#pragma unroll
    for (int c = 0; c < 4; c++) {
      int n0  = bm + wr * 64 + i * 16 + 4 * g;
      int col = bn + wc * 64 + c * 16 + l16;
      int b = n0 >> 11, n = n0 & 2047;
      int nc = col & 2047;
      int h = nc >> 6, dk = nc & 63;
      size_t hb = (size_t)(b * HEADS + h) * (NSEQ * DK);
      if (proj == 2) {
        size_t idx = hb + (size_t)(n >> 5) * 2048 + ((n >> 4) & 1) * 1024 +
                     (dk >> 5) * 512 + ((n >> 3) & 1) * 256 + (dk & 31) * 8 + (n & 7);
        s16x4 w;
#pragma unroll
        for (int r = 0; r < 4; r++) w[r] = f2b(acc[i][c][r]);
        *reinterpret_cast<s16x4*>(Vb + idx) = w;
      } else {
#pragma unroll
        for (int r = 0; r < 4; r++) {
          int nr = n + r;
          size_t idx = hb + (size_t)(nr >> 5) * 2048 + (dk >> 4) * 512 +
                       ((dk >> 3) & 1) * 256 + (nr & 31) * 8 + (dk & 7);
          float v = acc[i][c][r];
          if (proj == 0) Qb[idx] = f2b(v * 0.18033688f);  // 0.125*log2(e)
          else           Kb[idx] = f2b(v);
        }
      }
    }
}

// -------- output projection GEMM: M=4096, N=512, K=2048, f32 out + bias --------
__global__ __launch_bounds__(256) void k_gemm_out(const short* __restrict__ A,
                                                  const short* __restrict__ Bw,
                                                  float* __restrict__ out,
                                                  const float* __restrict__ bias) {
  __shared__ short sA[2][4096];
  __shared__ short sB[2][4096];
  const int bm = blockIdx.x * 64;
  const int bn = blockIdx.y * 64;
  const int wave = threadIdx.x >> 6, lane = threadIdx.x & 63;
  const int l16 = lane & 15, g = lane >> 4;
  const int wr = wave >> 1, wc = wave & 1;

  const short* Au = A + (size_t)(bm >> 4) * 32768 + lane * 8;
  const short* Bu = Bw + (size_t)(bn >> 4) * 32768 + lane * 8;

  f32x4 acc[2][2] = {};

  auto stage = [&](int buf, int kt) {
    gll16(Au + (size_t)wave * 32768 + (2 * kt)     * 512, &sA[buf][(wave * 2 + 0) * 512]);
    gll16(Au + (size_t)wave * 32768 + (2 * kt + 1) * 512, &sA[buf][(wave * 2 + 1) * 512]);
    gll16(Bu + (size_t)wave * 32768 + (2 * kt)     * 512, &sB[buf][(wave * 2 + 0) * 512]);
    gll16(Bu + (size_t)wave * 32768 + (2 * kt + 1) * 512, &sB[buf][(wave * 2 + 1) * 512]);
  };

  stage(0, 0);
  __syncthreads();
  int cur = 0;
  for (int kt = 0; kt < 32; ++kt) {
    if (kt + 1 < 32) stage(cur ^ 1, kt + 1);
#pragma unroll
    for (int ku = 0; ku < 2; ++ku) {
      s16x8 a[2], b[2];
#pragma unroll
      for (int i = 0; i < 2; i++)
        a[i] = *reinterpret_cast<const s16x8*>(
            &sA[cur][((wr * 2 + i) * 2 + ku) * 512 + lane * 8]);
#pragma unroll
      for (int c = 0; c < 2; c++)
        b[c] = *reinterpret_cast<const s16x8*>(
            &sB[cur][((wc * 2 + c) * 2 + ku) * 512 + lane * 8]);
#pragma unroll
      for (int i = 0; i < 2; i++)
#pragma unroll
        for (int c = 0; c < 2; c++)
          acc[i][c] = __builtin_amdgcn_mfma_f32_16x16x32_bf16(a[i], b[c], acc[i][c], 0, 0, 0);
    }
    if (kt + 1 < 32) { __syncthreads(); cur ^= 1; }
  }

#pragma unroll
  for (int i = 0; i < 2; i++)
#pragma unroll
    for (int c = 0; c < 2; c++)
#pragma unroll
      for (int r = 0; r < 4; r++) {
        int row = bm + wr * 32 + i * 16 + 4 * g + r;
        int col = bn + wc * 32 + c * 16 + l16;
        out[(size_t)row * 512 + col] = acc[i][c][r] + bias[col];
      }
}

// ------- flash attention: 64 q-rows/wave, KV-PAIR unroll (4 indep chains) -----
// Per iteration: tiles {t,t+1}. 16 independent QK MFMAs issue back-to-back;
// V loads for both tiles issue under them (L2-hit ~200cy, XCD swizzle keeps
// K/V L2-resident); PV(t) overlaps softmax(t+1) in the issue stream.
// K regs die after QK -> peak live ~205 VGPR (2 waves/SIMD preserved).
__global__ __launch_bounds__(128) void k_attn(const short* __restrict__ Q,
                                              const short* __restrict__ K,
                                              const short* __restrict__ VT,
                                              short* __restrict__ att) {
  const int wave = threadIdx.x >> 6, lane = threadIdx.x & 63;
  const int l32 = lane & 31, hi = lane >> 5;
  const int bid = blockIdx.x;                  // 0..1023, XCD-aware decode (T1)
  const int xcd = bid & 7, slot = bid >> 3;
  const int g = xcd * 8 + (slot >> 4);         // (b,h) group 0..63
  const int qt = slot & 15;
  const int h = g & 31, b = g >> 5;
  const int q0 = qt * 128 + wave * 64;
  const size_t hb = ((size_t)b * HEADS + h) * (size_t)NSEQ * DK;
  const short* Qh = Q + hb;
  const short* Kh = K + hb;
  const short* Vh = VT + hb;

  // Q B-frags for both 32-row groups (held whole kernel)
  s16x8 qfA[4], qfB[4];
  {
    const short* qa = Qh + (size_t)(q0 >> 5) * 2048 + lane * 8;
#pragma unroll
    for (int c = 0; c < 4; c++) qfA[c] = *reinterpret_cast<const s16x8*>(qa + c * 512);
    const short* qb2 = qa + 2048;
#pragma unroll
    for (int c = 0; c < 4; c++) qfB[c] = *reinterpret_cast<const s16x8*>(qb2 + c * 512);
  }

  f32x16 otA[2] = {}, otB[2] = {};
  float lsA = 0.f, lsB = 0.f;

  constexpr int NT = NSEQ / 32;

  // max-free softmax on one score fragment -> P^T B-frags (T12 permlane route)
  auto softmax_frag = [&](f32x16& st, float& ls, s16x8& pf0, s16x8& pf1) {
    float p[16];
#pragma unroll
    for (int r = 0; r < 16; r++) p[r] = __builtin_amdgcn_exp2f(st[r]);
    f32x2 e0 = (f32x2){p[0], p[1]} + (f32x2){p[2], p[3]};
    f32x2 e1 = (f32x2){p[4], p[5]} + (f32x2){p[6], p[7]};
    f32x2 e2 = (f32x2){p[8], p[9]} + (f32x2){p[10], p[11]};
    f32x2 e3 = (f32x2){p[12], p[13]} + (f32x2){p[14], p[15]};
    e0 += e1; e2 += e3; e0 += e2;
    ls += xhalf_add(e0[0] + e0[1]);
    unsigned a0 = cvt_pk_bf16(p[0], p[1]),   a1 = cvt_pk_bf16(p[2], p[3]);
    unsigned a2 = cvt_pk_bf16(p[4], p[5]),   a3 = cvt_pk_bf16(p[6], p[7]);
    unsigned a4 = cvt_pk_bf16(p[8], p[9]),   a5 = cvt_pk_bf16(p[10], p[11]);
    unsigned a6 = cvt_pk_bf16(p[12], p[13]), a7 = cvt_pk_bf16(p[14], p[15]);
    u32x2 w0 = __builtin_amdgcn_permlane32_swap(a0, a2, false, false);
    u32x2 w1 = __builtin_amdgcn_permlane32_swap(a1, a3, false, false);
    u32x2 w2 = __builtin_amdgcn_permlane32_swap(a4, a6, false, false);
    u32x2 w3 = __builtin_amdgcn_permlane32_swap(a5, a7, false, false);
    u32x4 pw0 = {w0[0], w1[0], w0[1], w1[1]};
    u32x4 pw1 = {w2[0], w3[0], w2[1], w3[1]};
    pf0 = __builtin_bit_cast(s16x8, pw0);
    pf1 = __builtin_bit_cast(s16x8, pw1);
  };

  for (int t = 0; t < NT; t += 2) {
    // K frags for both tiles of the pair
    const short* kb0 = Kh + (size_t)t * 2048 + lane * 8;
    const short* kb1 = kb0 + 2048;
    s16x8 k0[4], k1[4];
#pragma unroll
    for (int c = 0; c < 4; c++) k0[c] = *reinterpret_cast<const s16x8*>(kb0 + c * 512);
#pragma unroll
    for (int c = 0; c < 4; c++) k1[c] = *reinterpret_cast<const s16x8*>(kb1 + c * 512);

    // 16 independent QK MFMAs: 4 chains of 4 (2 q-groups x 2 kv-tiles)
    f32x16 s0A = {}, s0B = {}, s1A = {}, s1B = {};
#pragma unroll
    for (int c = 0; c < 4; c++) {
      s0A = __builtin_amdgcn_mfma_f32_32x32x16_bf16(k0[c], qfA[c], s0A, 0, 0, 0);
      s0B = __builtin_amdgcn_mfma_f32_32x32x16_bf16(k0[c], qfB[c], s0B, 0, 0, 0);
      s1A = __builtin_amdgcn_mfma_f32_32x32x16_bf16(k1[c], qfA[c], s1A, 0, 0, 0);
      s1B = __builtin_amdgcn_mfma_f32_32x32x16_bf16(k1[c], qfB[c], s1B, 0, 0, 0);
    }

    // V frags for both tiles — issued while QK chews; land before PV needs them
    const short* vb0 = Vh + (size_t)t * 2048 + lane * 8;
    const short* vb1 = vb0 + 2048;
    s16x8 v000 = *reinterpret_cast<const s16x8*>(vb0);
    s16x8 v001 = *reinterpret_cast<const s16x8*>(vb0 + 512);
    s16x8 v010 = *reinterpret_cast<const s16x8*>(vb0 + 1024);
    s16x8 v011 = *reinterpret_cast<const s16x8*>(vb0 + 1536);
    s16x8 v100 = *reinterpret_cast<const s16x8*>(vb1);
    s16x8 v101 = *reinterpret_cast<const s16x8*>(vb1 + 512);
    s16x8 v110 = *reinterpret_cast<const s16x8*>(vb1 + 1024);
    s16x8 v111 = *reinterpret_cast<const s16x8*>(vb1 + 1536);

    // tile t: softmax + PV (PV matrix work overlaps softmax(t+1) below)
    s16x8 pA0, pA1, pB0, pB1;
    softmax_frag(s0A, lsA, pA0, pA1);
    softmax_frag(s0B, lsB, pB0, pB1);
    otA[0] = __builtin_amdgcn_mfma_f32_32x32x16_bf16(v000, pA0, otA[0], 0, 0, 0);
    otA[1] = __builtin_amdgcn_mfma_f32_32x32x16_bf16(v001, pA0, otA[1], 0, 0, 0);
    otB[0] = __builtin_amdgcn_mfma_f32_32x32x16_bf16(v000, pB0, otB[0], 0, 0, 0);
    otB[1] = __builtin_amdgcn_mfma_f32_32x32x16_bf16(v001, pB0, otB[1], 0, 0, 0);
    otA[0] = __builtin_amdgcn_mfma_f32_32x32x16_bf16(v010, pA1, otA[0], 0, 0, 0);
    otA[1] = __builtin_amdgcn_mfma_f32_32x32x16_bf16(v011, pA1, otA[1], 0, 0, 0);
    otB[0] = __builtin_amdgcn_mfma_f32_32x32x16_bf16(v010, pB1, otB[0], 0, 0, 0);
    otB[1] = __builtin_amdgcn_mfma_f32_32x32x16_bf16(v011, pB1, otB[1], 0, 0, 0);

    // tile t+1: softmax + PV
    softmax_frag(s1A, lsA, pA0, pA1);
    softmax_frag(s1B, lsB, pB0, pB1);
    otA[0] = __builtin_amdgcn_mfma_f32_32x32x16_bf16(v100, pA0, otA[0], 0, 0, 0);
    otA[1] = __builtin_amdgcn_mfma_f32_32x32x16_bf16(v101, pA0, otA[1], 0, 0, 0);
    otB[0] = __builtin_amdgcn_mfma_f32_32x32x16_bf16(v100, pB0, otB[0], 0, 0, 0);
    otB[1] = __builtin_amdgcn_mfma_f32_32x32x16_bf16(v101, pB0, otB[1], 0, 0, 0);
    otA[0] = __builtin_amdgcn_mfma_f32_32x32x16_bf16(v110, pA1, otA[0], 0, 0, 0);
    otA[1] = __builtin_amdgcn_mfma_f32_32x32x16_bf16(v111, pA1, otA[1], 0, 0, 0);
    otB[0] = __builtin_amdgcn_mfma_f32_32x32x16_bf16(v110, pB1, otB[0], 0, 0, 0);
    otB[1] = __builtin_amdgcn_mfma_f32_32x32x16_bf16(v111, pB1, otB[1], 0, 0, 0);
  }

  // epilogue: normalize + write att in A-frag-linear (unit stride 32768, K=2048)
  auto wout = [&](f32x16(&ot)[2], float ls, int qq) {
    float inv = 1.f / ls;
    size_t aunit = ((size_t)(b * 128) + (size_t)((qq + l32) >> 4)) * 32768;
    const int mr = l32 & 15;
#pragma unroll
    for (int dt = 0; dt < 2; dt++)
#pragma unroll
      for (int gq = 0; gq < 4; gq++) {
        s16x4 w;
#pragma unroll
        for (int j = 0; j < 4; j++) w[j] = f2b(ot[dt][4 * gq + j] * inv);
        size_t base = aunit + (size_t)(h * 2 + dt) * 512 + gq * 128 + mr * 8 + 4 * hi;
        *reinterpret_cast<s16x4*>(att + base) = w;
      }
  };
  wout(otA, lsA, q0);
  wout(otB, lsB, q0 + 32);
}

extern "C" void kernel_launch(void* const* d_in, const int* in_sizes, int n_in,
                              void* d_out, int out_size, void* d_ws, size_t ws_size,
                              hipStream_t stream) {
  const float* x  = (const float*)d_in[0];
  const float* Wq = (const float*)d_in[1];
  const float* Wk = (const float*)d_in[2];
  const float* Wv = (const float*)d_in[3];
  const float* Wz = (const float*)d_in[4];
  const float* bz = (const float*)d_in[5];

  char* ws = (char*)d_ws;
  const size_t MB = (size_t)1 << 20;
  short* xb   = (short*)(ws);             // A-frag-linear x    4 MB
  short* wqkv = (short*)(ws + 4 * MB);    // B-frag-linear QKV  6 MB
  short* wzt  = (short*)(ws + 10 * MB);   // B-frag-linear Wz   2 MB
  short* Qb   = (short*)(ws + 12 * MB);   // attn Q layout     16 MB
  short* Kb   = (short*)(ws + 28 * MB);   // attn K layout     16 MB
  short* Vt   = (short*)(ws + 44 * MB);   // attn V layout     16 MB
  short* att  = (short*)(ws + 60 * MB);   // A-frag-linear att 16 MB

  k_prep<<<2048, 256, 0, stream>>>(x, Wq, Wk, Wv, Wz, xb, wqkv, wzt);

  k_gemm_qkv<<<dim3(32, 48), 256, 0, stream>>>(xb, wqkv, Qb, Kb, Vt);

  k_attn<<<1024, 128, 0, stream>>>(Qb, Kb, Vt, att);

  k_gemm_out<<<dim3(64, 8), 256, 0, stream>>>(att, wzt, (float*)d_out, bz);
}

// Round 17
// 156.961 us; speedup vs baseline: 1.1650x; 1.1650x over previous
//
#include <hip/hip_runtime.h>

#define HEADS 32
#define DK    64
#define NSEQ  2048
#define BATCH 2
#define DIN   512
#define INNER 2048  // HEADS*DK

typedef float f32x2 __attribute__((ext_vector_type(2)));
typedef float f32x4 __attribute__((ext_vector_type(4)));
typedef float f32x16 __attribute__((ext_vector_type(16)));
typedef short s16x8 __attribute__((ext_vector_type(8)));
typedef short s16x4 __attribute__((ext_vector_type(4)));
typedef unsigned u32x2 __attribute__((ext_vector_type(2)));
typedef unsigned u32x4 __attribute__((ext_vector_type(4)));

#define AS1 __attribute__((address_space(1)))
#define AS3 __attribute__((address_space(3)))

__device__ __forceinline__ short f2b(float f) {
  unsigned u = __float_as_uint(f);
  u += 0x7fffu + ((u >> 16) & 1u);   // round-to-nearest-even
  return (short)(u >> 16);
}

__device__ __forceinline__ unsigned cvt_pk_bf16(float lo, float hi) {
  unsigned r;
  asm("v_cvt_pk_bf16_f32 %0, %1, %2" : "=v"(r) : "v"(lo), "v"(hi));
  return r;
}

// cross-half (lane ^ 32) add via permlane32_swap (full-rate VALU, no LDS)
__device__ __forceinline__ float xhalf_add(float v) {
  u32x2 r = __builtin_amdgcn_permlane32_swap(__float_as_uint(v), __float_as_uint(v),
                                             false, false);
  return __uint_as_float(r[0]) + __uint_as_float(r[1]);
}

// async global->LDS, 16B per lane; lds dest = wave-uniform base + lane*16
__device__ __forceinline__ void gll16(const short* gp, short* lp) {
  __builtin_amdgcn_global_load_lds((const AS1 unsigned*)gp, (AS3 unsigned*)lp, 16, 0, 0);
}

// A-frag-linear (16x16x32 A operand), unit = 16 rows x 32 k = 512 shorts:
//   lin = (m>>4)*(K*16) + (k>>5)*512 + (m&15)*8 + ((k>>3)&3)*128 + (k&7)
// B-frag-linear identical with n in place of m.
// Q/K attn layout per (b,h): lin = (n>>5)*2048 + (dk>>4)*512 + ((dk>>3)&1)*256 + (n&31)*8 + (dk&7)
// V  attn layout per (b,h): lin = (n>>5)*2048 + ((n>>4)&1)*1024 + (dk>>5)*512 + ((n>>3)&1)*256 + (dk&31)*8 + (n&7)

// ---------- fused preprocessing: cvt(x) + transpose(Wq,Wk,Wv,Wz), one launch ----------
__global__ __launch_bounds__(256) void k_prep(const float* __restrict__ x,
                                              const float* __restrict__ Wq,
                                              const float* __restrict__ Wk,
                                              const float* __restrict__ Wv,
                                              const float* __restrict__ Wz,
                                              short* __restrict__ xb,
                                              short* __restrict__ wqkv,
                                              short* __restrict__ wzt) {
  const int bid = blockIdx.x;
  if (bid < 1024) {
    int t = bid * 256 + threadIdx.x;
    int m = t >> 6, kc = t & 63;
    const float* src = x + (size_t)m * 512 + kc * 8;
    float4 v0 = *reinterpret_cast<const float4*>(src);
    float4 v1 = *reinterpret_cast<const float4*>(src + 4);
    s16x8 o;
    o[0] = f2b(v0.x); o[1] = f2b(v0.y); o[2] = f2b(v0.z); o[3] = f2b(v0.w);
    o[4] = f2b(v1.x); o[5] = f2b(v1.y); o[6] = f2b(v1.z); o[7] = f2b(v1.w);
    size_t lin = (size_t)(m >> 4) * 8192 + (kc >> 2) * 512 + (kc & 3) * 128 + (m & 15) * 8;
    *reinterpret_cast<s16x8*>(xb + lin) = o;
    return;
  }
  __shared__ float tile[64][65];
  const float* in; short* out; int R, C, bx, by;
  if (bid < 1792) {
    int z = (bid - 1024) >> 8, inner = (bid - 1024) & 255;
    in = z == 0 ? Wq : z == 1 ? Wk : Wv;
    out = wqkv + (size_t)z * 1048576;
    R = DIN; C = INNER;
    bx = inner & 31; by = inner >> 5;
  } else {
    int inner = bid - 1792;
    in = Wz; out = wzt; R = INNER; C = DIN;
    bx = inner & 7; by = inner >> 3;
  }
  const int tc = bx * 64, tr = by * 64;
  const int tx = threadIdx.x & 63;
  const int ty = threadIdx.x >> 6;
#pragma unroll
  for (int rr = ty; rr < 64; rr += 4)
    tile[rr][tx] = in[(size_t)(tr + rr) * C + tc + tx];
  __syncthreads();
#pragma unroll
  for (int rr = ty; rr < 64; rr += 4) {
    int n = tc + rr, k = tr + tx;
    size_t lin = (size_t)(n >> 4) * ((size_t)R * 16) + (k >> 5) * 512 +
                 ((k >> 3) & 3) * 128 + (n & 15) * 8 + (k & 7);
    out[lin] = f2b(tile[tx][rr]);
  }
}

// -------- fused QKV projection GEMM: M=4096, N=6144, K=512 --------
__global__ __launch_bounds__(256) void k_gemm_qkv(const short* __restrict__ A,
                                                  const short* __restrict__ Bw,
                                                  short* __restrict__ Qb,
                                                  short* __restrict__ Kb,
                                                  short* __restrict__ Vb) {
  __shared__ short sA[2][4096];
  __shared__ short sB[2][4096];
  const int bm = blockIdx.x * 128;
  const int bn = blockIdx.y * 128;
  const int wave = threadIdx.x >> 6, lane = threadIdx.x & 63;
  const int l16 = lane & 15, g = lane >> 4;
  const int wr = wave >> 1, wc = wave & 1;

  const short* Au = A + ((size_t)(bm >> 4) + wave) * 8192 + lane * 8;
  const short* Bu = Bw + ((size_t)(bn >> 4) + wave) * 8192 + lane * 8;

  f32x4 acc[4][4] = {};

  auto stage = [&](int buf, int kt) {
    gll16(Au + kt * 512,              &sA[buf][wave * 512]);
    gll16(Au + 4 * 8192 + kt * 512,   &sA[buf][(wave + 4) * 512]);
    gll16(Bu + kt * 512,              &sB[buf][wave * 512]);
    gll16(Bu + 4 * 8192 + kt * 512,   &sB[buf][(wave + 4) * 512]);
  };

  stage(0, 0);
  __syncthreads();
  int cur = 0;
  for (int kt = 0; kt < 16; ++kt) {
    if (kt + 1 < 16) stage(cur ^ 1, kt + 1);
    s16x8 a[4], b[4];
#pragma unroll
    for (int i = 0; i < 4; i++)
      a[i] = *reinterpret_cast<const s16x8*>(&sA[cur][(wr * 4 + i) * 512 + lane * 8]);
#pragma unroll
    for (int c = 0; c < 4; c++)
      b[c] = *reinterpret_cast<const s16x8*>(&sB[cur][(wc * 4 + c) * 512 + lane * 8]);
#pragma unroll
    for (int i = 0; i < 4; i++)
#pragma unroll
      for (int c = 0; c < 4; c++)
        acc[i][c] = __builtin_amdgcn_mfma_f32_16x16x32_bf16(a[i], b[c], acc[i][c], 0, 0, 0);
    if (kt + 1 < 16) { __syncthreads(); cur ^= 1; }
  }

  const int proj = bn >> 11;
#pragma unroll
  for (int i = 0; i < 4; i++)
#pragma unroll
    for (int c = 0; c < 4; c++) {
      int n0  = bm + wr * 64 + i * 16 + 4 * g;
      int col = bn + wc * 64 + c * 16 + l16;
      int b = n0 >> 11, n = n0 & 2047;
      int nc = col & 2047;
      int h = nc >> 6, dk = nc & 63;
      size_t hb = (size_t)(b * HEADS + h) * (NSEQ * DK);
      if (proj == 2) {
        size_t idx = hb + (size_t)(n >> 5) * 2048 + ((n >> 4) & 1) * 1024 +
                     (dk >> 5) * 512 + ((n >> 3) & 1) * 256 + (dk & 31) * 8 + (n & 7);
        s16x4 w;
#pragma unroll
        for (int r = 0; r < 4; r++) w[r] = f2b(acc[i][c][r]);
        *reinterpret_cast<s16x4*>(Vb + idx) = w;
      } else {
#pragma unroll
        for (int r = 0; r < 4; r++) {
          int nr = n + r;
          size_t idx = hb + (size_t)(nr >> 5) * 2048 + (dk >> 4) * 512 +
                       ((dk >> 3) & 1) * 256 + (nr & 31) * 8 + (dk & 7);
          float v = acc[i][c][r];
          if (proj == 0) Qb[idx] = f2b(v * 0.18033688f);  // 0.125*log2(e)
          else           Kb[idx] = f2b(v);
        }
      }
    }
}

// -------- output projection GEMM: M=4096, N=512, K=2048, f32 out + bias --------
__global__ __launch_bounds__(256) void k_gemm_out(const short* __restrict__ A,
                                                  const short* __restrict__ Bw,
                                                  float* __restrict__ out,
                                                  const float* __restrict__ bias) {
  __shared__ short sA[2][4096];
  __shared__ short sB[2][4096];
  const int bm = blockIdx.x * 64;
  const int bn = blockIdx.y * 64;
  const int wave = threadIdx.x >> 6, lane = threadIdx.x & 63;
  const int l16 = lane & 15, g = lane >> 4;
  const int wr = wave >> 1, wc = wave & 1;

  const short* Au = A + (size_t)(bm >> 4) * 32768 + lane * 8;
  const short* Bu = Bw + (size_t)(bn >> 4) * 32768 + lane * 8;

  f32x4 acc[2][2] = {};

  auto stage = [&](int buf, int kt) {
    gll16(Au + (size_t)wave * 32768 + (2 * kt)     * 512, &sA[buf][(wave * 2 + 0) * 512]);
    gll16(Au + (size_t)wave * 32768 + (2 * kt + 1) * 512, &sA[buf][(wave * 2 + 1) * 512]);
    gll16(Bu + (size_t)wave * 32768 + (2 * kt)     * 512, &sB[buf][(wave * 2 + 0) * 512]);
    gll16(Bu + (size_t)wave * 32768 + (2 * kt + 1) * 512, &sB[buf][(wave * 2 + 1) * 512]);
  };

  stage(0, 0);
  __syncthreads();
  int cur = 0;
  for (int kt = 0; kt < 32; ++kt) {
    if (kt + 1 < 32) stage(cur ^ 1, kt + 1);
#pragma unroll
    for (int ku = 0; ku < 2; ++ku) {
      s16x8 a[2], b[2];
#pragma unroll
      for (int i = 0; i < 2; i++)
        a[i] = *reinterpret_cast<const s16x8*>(
            &sA[cur][((wr * 2 + i) * 2 + ku) * 512 + lane * 8]);
#pragma unroll
      for (int c = 0; c < 2; c++)
        b[c] = *reinterpret_cast<const s16x8*>(
            &sB[cur][((wc * 2 + c) * 2 + ku) * 512 + lane * 8]);
#pragma unroll
      for (int i = 0; i < 2; i++)
#pragma unroll
        for (int c = 0; c < 2; c++)
          acc[i][c] = __builtin_amdgcn_mfma_f32_16x16x32_bf16(a[i], b[c], acc[i][c], 0, 0, 0);
    }
    if (kt + 1 < 32) { __syncthreads(); cur ^= 1; }
  }

#pragma unroll
  for (int i = 0; i < 2; i++)
#pragma unroll
    for (int c = 0; c < 2; c++)
#pragma unroll
      for (int r = 0; r < 4; r++) {
        int row = bm + wr * 32 + i * 16 + 4 * g + r;
        int col = bn + wc * 32 + c * 16 + l16;
        out[(size_t)row * 512 + col] = acc[i][c][r] + bias[col];
      }
}

// ---------------- flash attention: 64 q-rows per wave, max-free softmax -------
// r15 body verbatim (best-known: 78.4us) + T5 s_setprio around MFMA clusters.
// 2 independent waves/SIMD at different phases -> setprio has role diversity
// to arbitrate (m191 regime, not m190's lockstep null).
__global__ __launch_bounds__(128) void k_attn(const short* __restrict__ Q,
                                              const short* __restrict__ K,
                                              const short* __restrict__ VT,
                                              short* __restrict__ att) {
  const int wave = threadIdx.x >> 6, lane = threadIdx.x & 63;
  const int l32 = lane & 31, hi = lane >> 5;
  const int bid = blockIdx.x;                  // 0..1023, XCD-aware decode (T1)
  const int xcd = bid & 7, slot = bid >> 3;
  const int g = xcd * 8 + (slot >> 4);         // (b,h) group 0..63
  const int qt = slot & 15;
  const int h = g & 31, b = g >> 5;
  const int q0 = qt * 128 + wave * 64;
  const size_t hb = ((size_t)b * HEADS + h) * (size_t)NSEQ * DK;
  const short* Qh = Q + hb;
  const short* Kh = K + hb;
  const short* Vh = VT + hb;

  // Q B-frags for both 32-row groups (held whole kernel)
  s16x8 qfA[4], qfB[4];
  {
    const short* qa = Qh + (size_t)(q0 >> 5) * 2048 + lane * 8;
#pragma unroll
    for (int c = 0; c < 4; c++) qfA[c] = *reinterpret_cast<const s16x8*>(qa + c * 512);
    const short* qb2 = qa + 2048;
#pragma unroll
    for (int c = 0; c < 4; c++) qfB[c] = *reinterpret_cast<const s16x8*>(qb2 + c * 512);
  }

  f32x16 otA[2] = {}, otB[2] = {};
  float lsA = 0.f, lsB = 0.f;

  constexpr int NT = NSEQ / 32;
  s16x8 kfA[4], kfB[4];
  {
    const short* kbase = Kh + lane * 8;
#pragma unroll
    for (int c = 0; c < 4; c++) kfA[c] = *reinterpret_cast<const s16x8*>(kbase + c * 512);
  }

  // max-free softmax on one score fragment -> P^T B-frags (T12 permlane route)
  auto softmax_frag = [&](f32x16& st, float& ls, s16x8& pf0, s16x8& pf1) {
    float p[16];
#pragma unroll
    for (int r = 0; r < 16; r++) p[r] = __builtin_amdgcn_exp2f(st[r]);
    f32x2 e0 = (f32x2){p[0], p[1]} + (f32x2){p[2], p[3]};
    f32x2 e1 = (f32x2){p[4], p[5]} + (f32x2){p[6], p[7]};
    f32x2 e2 = (f32x2){p[8], p[9]} + (f32x2){p[10], p[11]};
    f32x2 e3 = (f32x2){p[12], p[13]} + (f32x2){p[14], p[15]};
    e0 += e1; e2 += e3; e0 += e2;
    ls += xhalf_add(e0[0] + e0[1]);
    unsigned a0 = cvt_pk_bf16(p[0], p[1]),   a1 = cvt_pk_bf16(p[2], p[3]);
    unsigned a2 = cvt_pk_bf16(p[4], p[5]),   a3 = cvt_pk_bf16(p[6], p[7]);
    unsigned a4 = cvt_pk_bf16(p[8], p[9]),   a5 = cvt_pk_bf16(p[10], p[11]);
    unsigned a6 = cvt_pk_bf16(p[12], p[13]), a7 = cvt_pk_bf16(p[14], p[15]);
    u32x2 w0 = __builtin_amdgcn_permlane32_swap(a0, a2, false, false);
    u32x2 w1 = __builtin_amdgcn_permlane32_swap(a1, a3, false, false);
    u32x2 w2 = __builtin_amdgcn_permlane32_swap(a4, a6, false, false);
    u32x2 w3 = __builtin_amdgcn_permlane32_swap(a5, a7, false, false);
    u32x4 pw0 = {w0[0], w1[0], w0[1], w1[1]};
    u32x4 pw1 = {w2[0], w3[0], w2[1], w3[1]};
    pf0 = __builtin_bit_cast(s16x8, pw0);
    pf1 = __builtin_bit_cast(s16x8, pw1);
  };

  auto body = [&](s16x8(&kc)[4], s16x8(&kn)[4], int t) {
    // V A-frags (shared by both q-groups; independent -> issue first)
    const short* vbase = Vh + (size_t)t * 2048 + lane * 8;
    s16x8 vf00 = *reinterpret_cast<const s16x8*>(vbase);         // ks0, dt0
    s16x8 vf01 = *reinterpret_cast<const s16x8*>(vbase + 512);   // ks0, dt1
    s16x8 vf10 = *reinterpret_cast<const s16x8*>(vbase + 1024);  // ks1, dt0
    s16x8 vf11 = *reinterpret_cast<const s16x8*>(vbase + 1536);  // ks1, dt1

    // prefetch next K tile (clamped, branchless)
    int tn = (t + 1 < NT) ? t + 1 : t;
    const short* kbase = Kh + (size_t)tn * 2048 + lane * 8;
#pragma unroll
    for (int c = 0; c < 4; c++) kn[c] = *reinterpret_cast<const s16x8*>(kbase + c * 512);

    // two independent score chains (ILP)
    __builtin_amdgcn_s_setprio(1);
    f32x16 stA = {}, stB = {};
#pragma unroll
    for (int c = 0; c < 4; c++)
      stA = __builtin_amdgcn_mfma_f32_32x32x16_bf16(kc[c], qfA[c], stA, 0, 0, 0);
#pragma unroll
    for (int c = 0; c < 4; c++)
      stB = __builtin_amdgcn_mfma_f32_32x32x16_bf16(kc[c], qfB[c], stB, 0, 0, 0);
    __builtin_amdgcn_s_setprio(0);

    s16x8 pA0, pA1, pB0, pB1;
    softmax_frag(stA, lsA, pA0, pA1);
    softmax_frag(stB, lsB, pB0, pB1);

    // O^T += V^T . P^T for both groups
    __builtin_amdgcn_s_setprio(1);
    otA[0] = __builtin_amdgcn_mfma_f32_32x32x16_bf16(vf00, pA0, otA[0], 0, 0, 0);
    otA[1] = __builtin_amdgcn_mfma_f32_32x32x16_bf16(vf01, pA0, otA[1], 0, 0, 0);
    otB[0] = __builtin_amdgcn_mfma_f32_32x32x16_bf16(vf00, pB0, otB[0], 0, 0, 0);
    otB[1] = __builtin_amdgcn_mfma_f32_32x32x16_bf16(vf01, pB0, otB[1], 0, 0, 0);
    otA[0] = __builtin_amdgcn_mfma_f32_32x32x16_bf16(vf10, pA1, otA[0], 0, 0, 0);
    otA[1] = __builtin_amdgcn_mfma_f32_32x32x16_bf16(vf11, pA1, otA[1], 0, 0, 0);
    otB[0] = __builtin_amdgcn_mfma_f32_32x32x16_bf16(vf10, pB1, otB[0], 0, 0, 0);
    otB[1] = __builtin_amdgcn_mfma_f32_32x32x16_bf16(vf11, pB1, otB[1], 0, 0, 0);
    __builtin_amdgcn_s_setprio(0);
  };

  for (int t = 0; t < NT; t += 2) {
    body(kfA, kfB, t);
    body(kfB, kfA, t + 1);
  }

  // epilogue: normalize + write att in A-frag-linear (unit stride 32768, K=2048)
  auto wout = [&](f32x16(&ot)[2], float ls, int qq) {
    float inv = 1.f / ls;
    size_t aunit = ((size_t)(b * 128) + (size_t)((qq + l32) >> 4)) * 32768;
    const int mr = l32 & 15;
#pragma unroll
    for (int dt = 0; dt < 2; dt++)
#pragma unroll
      for (int gq = 0; gq < 4; gq++) {
        s16x4 w;
#pragma unroll
        for (int j = 0; j < 4; j++) w[j] = f2b(ot[dt][4 * gq + j] * inv);
        size_t base = aunit + (size_t)(h * 2 + dt) * 512 + gq * 128 + mr * 8 + 4 * hi;
        *reinterpret_cast<s16x4*>(att + base) = w;
      }
  };
  wout(otA, lsA, q0);
  wout(otB, lsB, q0 + 32);
}

extern "C" void kernel_launch(void* const* d_in, const int* in_sizes, int n_in,
                              void* d_out, int out_size, void* d_ws, size_t ws_size,
                              hipStream_t stream) {
  const float* x  = (const float*)d_in[0];
  const float* Wq = (const float*)d_in[1];
  const float* Wk = (const float*)d_in[2];
  const float* Wv = (const float*)d_in[3];
  const float* Wz = (const float*)d_in[4];
  const float* bz = (const float*)d_in[5];

  char* ws = (char*)d_ws;
  const size_t MB = (size_t)1 << 20;
  short* xb   = (short*)(ws);             // A-frag-linear x    4 MB
  short* wqkv = (short*)(ws + 4 * MB);    // B-frag-linear QKV  6 MB
  short* wzt  = (short*)(ws + 10 * MB);   // B-frag-linear Wz   2 MB
  short* Qb   = (short*)(ws + 12 * MB);   // attn Q layout     16 MB
  short* Kb   = (short*)(ws + 28 * MB);   // attn K layout     16 MB
  short* Vt   = (short*)(ws + 44 * MB);   // attn V layout     16 MB
  short* att  = (short*)(ws + 60 * MB);   // A-frag-linear att 16 MB

  k_prep<<<2048, 256, 0, stream>>>(x, Wq, Wk, Wv, Wz, xb, wqkv, wzt);

  k_gemm_qkv<<<dim3(32, 48), 256, 0, stream>>>(xb, wqkv, Qb, Kb, Vt);

  k_attn<<<1024, 128, 0, stream>>>(Qb, Kb, Vt, att);

  k_gemm_out<<<dim3(64, 8), 256, 0, stream>>>(att, wzt, (float*)d_out, bz);
}

// Round 18
// 152.053 us; speedup vs baseline: 1.2026x; 1.0323x over previous
//
#include <hip/hip_runtime.h>

#define HEADS 32
#define DK    64
#define NSEQ  2048
#define BATCH 2
#define DIN   512
#define INNER 2048  // HEADS*DK

typedef float f32x2 __attribute__((ext_vector_type(2)));
typedef float f32x4 __attribute__((ext_vector_type(4)));
typedef float f32x16 __attribute__((ext_vector_type(16)));
typedef short s16x8 __attribute__((ext_vector_type(8)));
typedef short s16x4 __attribute__((ext_vector_type(4)));
typedef unsigned u32x2 __attribute__((ext_vector_type(2)));
typedef unsigned u32x4 __attribute__((ext_vector_type(4)));

#define AS1 __attribute__((address_space(1)))
#define AS3 __attribute__((address_space(3)))

__device__ __forceinline__ short f2b(float f) {
  unsigned u = __float_as_uint(f);
  u += 0x7fffu + ((u >> 16) & 1u);   // round-to-nearest-even
  return (short)(u >> 16);
}

__device__ __forceinline__ unsigned cvt_pk_bf16(float lo, float hi) {
  unsigned r;
  asm("v_cvt_pk_bf16_f32 %0, %1, %2" : "=v"(r) : "v"(lo), "v"(hi));
  return r;
}

// cross-half (lane ^ 32) add via permlane32_swap (full-rate VALU, no LDS)
__device__ __forceinline__ float xhalf_add(float v) {
  u32x2 r = __builtin_amdgcn_permlane32_swap(__float_as_uint(v), __float_as_uint(v),
                                             false, false);
  return __uint_as_float(r[0]) + __uint_as_float(r[1]);
}

// async global->LDS, 16B per lane; lds dest = wave-uniform base + lane*16
__device__ __forceinline__ void gll16(const short* gp, short* lp) {
  __builtin_amdgcn_global_load_lds((const AS1 unsigned*)gp, (AS3 unsigned*)lp, 16, 0, 0);
}

// A-frag-linear (16x16x32 A operand), unit = 16 rows x 32 k = 512 shorts:
//   lin = (m>>4)*(K*16) + (k>>5)*512 + (m&15)*8 + ((k>>3)&3)*128 + (k&7)
// B-frag-linear identical with n in place of m.
// Q/K attn layout per (b,h): lin = (n>>5)*2048 + (dk>>4)*512 + ((dk>>3)&1)*256 + (n&31)*8 + (dk&7)
// V  attn layout per (b,h): lin = (n>>5)*2048 + ((n>>4)&1)*1024 + (dk>>5)*512 + ((n>>3)&1)*256 + (dk&31)*8 + (n&7)

// ---------- fused preprocessing: cvt(x) + transpose(Wq,Wk,Wv,Wz), one launch ----------
__global__ __launch_bounds__(256) void k_prep(const float* __restrict__ x,
                                              const float* __restrict__ Wq,
                                              const float* __restrict__ Wk,
                                              const float* __restrict__ Wv,
                                              const float* __restrict__ Wz,
                                              short* __restrict__ xb,
                                              short* __restrict__ wqkv,
                                              short* __restrict__ wzt) {
  const int bid = blockIdx.x;
  if (bid < 1024) {
    int t = bid * 256 + threadIdx.x;
    int m = t >> 6, kc = t & 63;
    const float* src = x + (size_t)m * 512 + kc * 8;
    float4 v0 = *reinterpret_cast<const float4*>(src);
    float4 v1 = *reinterpret_cast<const float4*>(src + 4);
    s16x8 o;
    o[0] = f2b(v0.x); o[1] = f2b(v0.y); o[2] = f2b(v0.z); o[3] = f2b(v0.w);
    o[4] = f2b(v1.x); o[5] = f2b(v1.y); o[6] = f2b(v1.z); o[7] = f2b(v1.w);
    size_t lin = (size_t)(m >> 4) * 8192 + (kc >> 2) * 512 + (kc & 3) * 128 + (m & 15) * 8;
    *reinterpret_cast<s16x8*>(xb + lin) = o;
    return;
  }
  __shared__ float tile[64][65];
  const float* in; short* out; int R, C, bx, by;
  if (bid < 1792) {
    int z = (bid - 1024) >> 8, inner = (bid - 1024) & 255;
    in = z == 0 ? Wq : z == 1 ? Wk : Wv;
    out = wqkv + (size_t)z * 1048576;
    R = DIN; C = INNER;
    bx = inner & 31; by = inner >> 5;
  } else {
    int inner = bid - 1792;
    in = Wz; out = wzt; R = INNER; C = DIN;
    bx = inner & 7; by = inner >> 3;
  }
  const int tc = bx * 64, tr = by * 64;
  const int tx = threadIdx.x & 63;
  const int ty = threadIdx.x >> 6;
#pragma unroll
  for (int rr = ty; rr < 64; rr += 4)
    tile[rr][tx] = in[(size_t)(tr + rr) * C + tc + tx];
  __syncthreads();
#pragma unroll
  for (int rr = ty; rr < 64; rr += 4) {
    int n = tc + rr, k = tr + tx;
    size_t lin = (size_t)(n >> 4) * ((size_t)R * 16) + (k >> 5) * 512 +
                 ((k >> 3) & 3) * 128 + (n & 15) * 8 + (k & 7);
    out[lin] = f2b(tile[tx][rr]);
  }
}

// -------- fused QKV projection GEMM: M=4096, N=6144, K=512 --------
__global__ __launch_bounds__(256) void k_gemm_qkv(const short* __restrict__ A,
                                                  const short* __restrict__ Bw,
                                                  short* __restrict__ Qb,
                                                  short* __restrict__ Kb,
                                                  short* __restrict__ Vb) {
  __shared__ short sA[2][4096];
  __shared__ short sB[2][4096];
  const int bm = blockIdx.x * 128;
  const int bn = blockIdx.y * 128;
  const int wave = threadIdx.x >> 6, lane = threadIdx.x & 63;
  const int l16 = lane & 15, g = lane >> 4;
  const int wr = wave >> 1, wc = wave & 1;

  const short* Au = A + ((size_t)(bm >> 4) + wave) * 8192 + lane * 8;
  const short* Bu = Bw + ((size_t)(bn >> 4) + wave) * 8192 + lane * 8;

  f32x4 acc[4][4] = {};

  auto stage = [&](int buf, int kt) {
    gll16(Au + kt * 512,              &sA[buf][wave * 512]);
    gll16(Au + 4 * 8192 + kt * 512,   &sA[buf][(wave + 4) * 512]);
    gll16(Bu + kt * 512,              &sB[buf][wave * 512]);
    gll16(Bu + 4 * 8192 + kt * 512,   &sB[buf][(wave + 4) * 512]);
  };

  stage(0, 0);
  __syncthreads();
  int cur = 0;
  for (int kt = 0; kt < 16; ++kt) {
    if (kt + 1 < 16) stage(cur ^ 1, kt + 1);
    s16x8 a[4], b[4];
#pragma unroll
    for (int i = 0; i < 4; i++)
      a[i] = *reinterpret_cast<const s16x8*>(&sA[cur][(wr * 4 + i) * 512 + lane * 8]);
#pragma unroll
    for (int c = 0; c < 4; c++)
      b[c] = *reinterpret_cast<const s16x8*>(&sB[cur][(wc * 4 + c) * 512 + lane * 8]);
#pragma unroll
    for (int i = 0; i < 4; i++)
#pragma unroll
      for (int c = 0; c < 4; c++)
        acc[i][c] = __builtin_amdgcn_mfma_f32_16x16x32_bf16(a[i], b[c], acc[i][c], 0, 0, 0);
    if (kt + 1 < 16) { __syncthreads(); cur ^= 1; }
  }

  const int proj = bn >> 11;
#pragma unroll
  for (int i = 0; i < 4; i++)
#pragma unroll
    for (int c = 0; c < 4; c++) {
      int n0  = bm + wr * 64 + i * 16 + 4 * g;
      int col = bn + wc * 64 + c * 16 + l16;
      int b = n0 >> 11, n = n0 & 2047;
      int nc = col & 2047;
      int h = nc >> 6, dk = nc & 63;
      size_t hb = (size_t)(b * HEADS + h) * (NSEQ * DK);
      if (proj == 2) {
        size_t idx = hb + (size_t)(n >> 5) * 2048 + ((n >> 4) & 1) * 1024 +
                     (dk >> 5) * 512 + ((n >> 3) & 1) * 256 + (dk & 31) * 8 + (n & 7);
        s16x4 w;
#pragma unroll
        for (int r = 0; r < 4; r++) w[r] = f2b(acc[i][c][r]);
        *reinterpret_cast<s16x4*>(Vb + idx) = w;
      } else {
#pragma unroll
        for (int r = 0; r < 4; r++) {
          int nr = n + r;
          size_t idx = hb + (size_t)(nr >> 5) * 2048 + (dk >> 4) * 512 +
                       ((dk >> 3) & 1) * 256 + (nr & 31) * 8 + (dk & 7);
          float v = acc[i][c][r];
          if (proj == 0) Qb[idx] = f2b(v * 0.18033688f);  // 0.125*log2(e)
          else           Kb[idx] = f2b(v);
        }
      }
    }
}

// -------- output projection GEMM: M=4096, N=512, K=2048, f32 out + bias --------
__global__ __launch_bounds__(256) void k_gemm_out(const short* __restrict__ A,
                                                  const short* __restrict__ Bw,
                                                  float* __restrict__ out,
                                                  const float* __restrict__ bias) {
  __shared__ short sA[2][4096];
  __shared__ short sB[2][4096];
  const int bm = blockIdx.x * 64;
  const int bn = blockIdx.y * 64;
  const int wave = threadIdx.x >> 6, lane = threadIdx.x & 63;
  const int l16 = lane & 15, g = lane >> 4;
  const int wr = wave >> 1, wc = wave & 1;

  const short* Au = A + (size_t)(bm >> 4) * 32768 + lane * 8;
  const short* Bu = Bw + (size_t)(bn >> 4) * 32768 + lane * 8;

  f32x4 acc[2][2] = {};

  auto stage = [&](int buf, int kt) {
    gll16(Au + (size_t)wave * 32768 + (2 * kt)     * 512, &sA[buf][(wave * 2 + 0) * 512]);
    gll16(Au + (size_t)wave * 32768 + (2 * kt + 1) * 512, &sA[buf][(wave * 2 + 1) * 512]);
    gll16(Bu + (size_t)wave * 32768 + (2 * kt)     * 512, &sB[buf][(wave * 2 + 0) * 512]);
    gll16(Bu + (size_t)wave * 32768 + (2 * kt + 1) * 512, &sB[buf][(wave * 2 + 1) * 512]);
  };

  stage(0, 0);
  __syncthreads();
  int cur = 0;
  for (int kt = 0; kt < 32; ++kt) {
    if (kt + 1 < 32) stage(cur ^ 1, kt + 1);
#pragma unroll
    for (int ku = 0; ku < 2; ++ku) {
      s16x8 a[2], b[2];
#pragma unroll
      for (int i = 0; i < 2; i++)
        a[i] = *reinterpret_cast<const s16x8*>(
            &sA[cur][((wr * 2 + i) * 2 + ku) * 512 + lane * 8]);
#pragma unroll
      for (int c = 0; c < 2; c++)
        b[c] = *reinterpret_cast<const s16x8*>(
            &sB[cur][((wc * 2 + c) * 2 + ku) * 512 + lane * 8]);
#pragma unroll
      for (int i = 0; i < 2; i++)
#pragma unroll
        for (int c = 0; c < 2; c++)
          acc[i][c] = __builtin_amdgcn_mfma_f32_16x16x32_bf16(a[i], b[c], acc[i][c], 0, 0, 0);
    }
    if (kt + 1 < 32) { __syncthreads(); cur ^= 1; }
  }

#pragma unroll
  for (int i = 0; i < 2; i++)
#pragma unroll
    for (int c = 0; c < 2; c++)
#pragma unroll
      for (int r = 0; r < 4; r++) {
        int row = bm + wr * 32 + i * 16 + 4 * g + r;
        int col = bn + wc * 32 + c * 16 + l16;
        out[(size_t)row * 512 + col] = acc[i][c][r] + bias[col];
      }
}

// ---------------- flash attention: 64 q-rows per wave, max-free softmax -------
// r15 body verbatim (best-known attn: 78.4us). XCD-aware decode (T1) kept.
// setprio removed (r17: -15%); pair-unroll removed (r16: -50%); split-KV
// merge abandoned (r12/r13: correctness).
__global__ __launch_bounds__(128) void k_attn(const short* __restrict__ Q,
                                              const short* __restrict__ K,
                                              const short* __restrict__ VT,
                                              short* __restrict__ att) {
  const int wave = threadIdx.x >> 6, lane = threadIdx.x & 63;
  const int l32 = lane & 31, hi = lane >> 5;
  const int bid = blockIdx.x;                  // 0..1023, XCD-aware decode (T1)
  const int xcd = bid & 7, slot = bid >> 3;
  const int g = xcd * 8 + (slot >> 4);         // (b,h) group 0..63
  const int qt = slot & 15;
  const int h = g & 31, b = g >> 5;
  const int q0 = qt * 128 + wave * 64;
  const size_t hb = ((size_t)b * HEADS + h) * (size_t)NSEQ * DK;
  const short* Qh = Q + hb;
  const short* Kh = K + hb;
  const short* Vh = VT + hb;

  // Q B-frags for both 32-row groups (held whole kernel)
  s16x8 qfA[4], qfB[4];
  {
    const short* qa = Qh + (size_t)(q0 >> 5) * 2048 + lane * 8;
#pragma unroll
    for (int c = 0; c < 4; c++) qfA[c] = *reinterpret_cast<const s16x8*>(qa + c * 512);
    const short* qb2 = qa + 2048;
#pragma unroll
    for (int c = 0; c < 4; c++) qfB[c] = *reinterpret_cast<const s16x8*>(qb2 + c * 512);
  }

  f32x16 otA[2] = {}, otB[2] = {};
  float lsA = 0.f, lsB = 0.f;

  constexpr int NT = NSEQ / 32;
  s16x8 kfA[4], kfB[4];
  {
    const short* kbase = Kh + lane * 8;
#pragma unroll
    for (int c = 0; c < 4; c++) kfA[c] = *reinterpret_cast<const s16x8*>(kbase + c * 512);
  }

  // max-free softmax on one score fragment -> P^T B-frags (T12 permlane route)
  auto softmax_frag = [&](f32x16& st, float& ls, s16x8& pf0, s16x8& pf1) {
    float p[16];
#pragma unroll
    for (int r = 0; r < 16; r++) p[r] = __builtin_amdgcn_exp2f(st[r]);
    f32x2 e0 = (f32x2){p[0], p[1]} + (f32x2){p[2], p[3]};
    f32x2 e1 = (f32x2){p[4], p[5]} + (f32x2){p[6], p[7]};
    f32x2 e2 = (f32x2){p[8], p[9]} + (f32x2){p[10], p[11]};
    f32x2 e3 = (f32x2){p[12], p[13]} + (f32x2){p[14], p[15]};
    e0 += e1; e2 += e3; e0 += e2;
    ls += xhalf_add(e0[0] + e0[1]);
    unsigned a0 = cvt_pk_bf16(p[0], p[1]),   a1 = cvt_pk_bf16(p[2], p[3]);
    unsigned a2 = cvt_pk_bf16(p[4], p[5]),   a3 = cvt_pk_bf16(p[6], p[7]);
    unsigned a4 = cvt_pk_bf16(p[8], p[9]),   a5 = cvt_pk_bf16(p[10], p[11]);
    unsigned a6 = cvt_pk_bf16(p[12], p[13]), a7 = cvt_pk_bf16(p[14], p[15]);
    u32x2 w0 = __builtin_amdgcn_permlane32_swap(a0, a2, false, false);
    u32x2 w1 = __builtin_amdgcn_permlane32_swap(a1, a3, false, false);
    u32x2 w2 = __builtin_amdgcn_permlane32_swap(a4, a6, false, false);
    u32x2 w3 = __builtin_amdgcn_permlane32_swap(a5, a7, false, false);
    u32x4 pw0 = {w0[0], w1[0], w0[1], w1[1]};
    u32x4 pw1 = {w2[0], w3[0], w2[1], w3[1]};
    pf0 = __builtin_bit_cast(s16x8, pw0);
    pf1 = __builtin_bit_cast(s16x8, pw1);
  };

  auto body = [&](s16x8(&kc)[4], s16x8(&kn)[4], int t) {
    // V A-frags (shared by both q-groups; independent -> issue first)
    const short* vbase = Vh + (size_t)t * 2048 + lane * 8;
    s16x8 vf00 = *reinterpret_cast<const s16x8*>(vbase);         // ks0, dt0
    s16x8 vf01 = *reinterpret_cast<const s16x8*>(vbase + 512);   // ks0, dt1
    s16x8 vf10 = *reinterpret_cast<const s16x8*>(vbase + 1024);  // ks1, dt0
    s16x8 vf11 = *reinterpret_cast<const s16x8*>(vbase + 1536);  // ks1, dt1

    // prefetch next K tile (clamped, branchless)
    int tn = (t + 1 < NT) ? t + 1 : t;
    const short* kbase = Kh + (size_t)tn * 2048 + lane * 8;
#pragma unroll
    for (int c = 0; c < 4; c++) kn[c] = *reinterpret_cast<const s16x8*>(kbase + c * 512);

    // two independent score chains (ILP)
    f32x16 stA = {}, stB = {};
#pragma unroll
    for (int c = 0; c < 4; c++)
      stA = __builtin_amdgcn_mfma_f32_32x32x16_bf16(kc[c], qfA[c], stA, 0, 0, 0);
#pragma unroll
    for (int c = 0; c < 4; c++)
      stB = __builtin_amdgcn_mfma_f32_32x32x16_bf16(kc[c], qfB[c], stB, 0, 0, 0);

    s16x8 pA0, pA1, pB0, pB1;
    softmax_frag(stA, lsA, pA0, pA1);
    softmax_frag(stB, lsB, pB0, pB1);

    // O^T += V^T . P^T for both groups
    otA[0] = __builtin_amdgcn_mfma_f32_32x32x16_bf16(vf00, pA0, otA[0], 0, 0, 0);
    otA[1] = __builtin_amdgcn_mfma_f32_32x32x16_bf16(vf01, pA0, otA[1], 0, 0, 0);
    otB[0] = __builtin_amdgcn_mfma_f32_32x32x16_bf16(vf00, pB0, otB[0], 0, 0, 0);
    otB[1] = __builtin_amdgcn_mfma_f32_32x32x16_bf16(vf01, pB0, otB[1], 0, 0, 0);
    otA[0] = __builtin_amdgcn_mfma_f32_32x32x16_bf16(vf10, pA1, otA[0], 0, 0, 0);
    otA[1] = __builtin_amdgcn_mfma_f32_32x32x16_bf16(vf11, pA1, otA[1], 0, 0, 0);
    otB[0] = __builtin_amdgcn_mfma_f32_32x32x16_bf16(vf10, pB1, otB[0], 0, 0, 0);
    otB[1] = __builtin_amdgcn_mfma_f32_32x32x16_bf16(vf11, pB1, otB[1], 0, 0, 0);
  };

  for (int t = 0; t < NT; t += 2) {
    body(kfA, kfB, t);
    body(kfB, kfA, t + 1);
  }

  // epilogue: normalize + write att in A-frag-linear (unit stride 32768, K=2048)
  auto wout = [&](f32x16(&ot)[2], float ls, int qq) {
    float inv = 1.f / ls;
    size_t aunit = ((size_t)(b * 128) + (size_t)((qq + l32) >> 4)) * 32768;
    const int mr = l32 & 15;
#pragma unroll
    for (int dt = 0; dt < 2; dt++)
#pragma unroll
      for (int gq = 0; gq < 4; gq++) {
        s16x4 w;
#pragma unroll
        for (int j = 0; j < 4; j++) w[j] = f2b(ot[dt][4 * gq + j] * inv);
        size_t base = aunit + (size_t)(h * 2 + dt) * 512 + gq * 128 + mr * 8 + 4 * hi;
        *reinterpret_cast<s16x4*>(att + base) = w;
      }
  };
  wout(otA, lsA, q0);
  wout(otB, lsB, q0 + 32);
}

extern "C" void kernel_launch(void* const* d_in, const int* in_sizes, int n_in,
                              void* d_out, int out_size, void* d_ws, size_t ws_size,
                              hipStream_t stream) {
  const float* x  = (const float*)d_in[0];
  const float* Wq = (const float*)d_in[1];
  const float* Wk = (const float*)d_in[2];
  const float* Wv = (const float*)d_in[3];
  const float* Wz = (const float*)d_in[4];
  const float* bz = (const float*)d_in[5];

  char* ws = (char*)d_ws;
  const size_t MB = (size_t)1 << 20;
  short* xb   = (short*)(ws);             // A-frag-linear x    4 MB
  short* wqkv = (short*)(ws + 4 * MB);    // B-frag-linear QKV  6 MB
  short* wzt  = (short*)(ws + 10 * MB);   // B-frag-linear Wz   2 MB
  short* Qb   = (short*)(ws + 12 * MB);   // attn Q layout     16 MB
  short* Kb   = (short*)(ws + 28 * MB);   // attn K layout     16 MB
  short* Vt   = (short*)(ws + 44 * MB);   // attn V layout     16 MB
  short* att  = (short*)(ws + 60 * MB);   // A-frag-linear att 16 MB

  k_prep<<<2048, 256, 0, stream>>>(x, Wq, Wk, Wv, Wz, xb, wqkv, wzt);

  k_gemm_qkv<<<dim3(32, 48), 256, 0, stream>>>(xb, wqkv, Qb, Kb, Vt);

  k_attn<<<1024, 128, 0, stream>>>(Qb, Kb, Vt, att);

  k_gemm_out<<<dim3(64, 8), 256, 0, stream>>>(att, wzt, (float*)d_out, bz);
}